// Round 4
// baseline (268.950 us; speedup 1.0000x reference)
//
#include <hip/hip_runtime.h>

#define BATCH 8192
#define FEATS 4096
#define RCHUNKS 256
#define ROWS_PER_CHUNK (BATCH / RCHUNKS)  // 32

typedef float v4f __attribute__((ext_vector_type(4)));  // native vector: ok for nontemporal builtins

// ws layout: [0, RCHUNKS*FEATS) doubles = partial column sums (8 MB)
//            + FEATS doubles = means
//            + 16 doubles = block mins, + 16 doubles = block maxs
//            + FEATS floats = per-feature scale

__global__ __launch_bounds__(256) void colsum_part(const float* __restrict__ in,
                                                   double* __restrict__ partials) {
    // grid = (4 col groups of 1024, RCHUNKS row chunks)
    const int colBase = blockIdx.x * 1024 + threadIdx.x * 4;
    const int row0 = blockIdx.y * ROWS_PER_CHUNK;
    const v4f* p = (const v4f*)in + (size_t)row0 * (FEATS / 4) + (colBase >> 2);
    double a0 = 0.0, a1 = 0.0, a2 = 0.0, a3 = 0.0;
#pragma unroll 8
    for (int r = 0; r < ROWS_PER_CHUNK; ++r) {
        v4f v = p[(size_t)r * (FEATS / 4)];
        a0 += (double)v.x; a1 += (double)v.y; a2 += (double)v.z; a3 += (double)v.w;
    }
    double* dst = partials + (size_t)blockIdx.y * FEATS + colBase;
    dst[0] = a0; dst[1] = a1; dst[2] = a2; dst[3] = a3;
}

__global__ __launch_bounds__(256) void reduce_mean(const double* __restrict__ partials,
                                                   double* __restrict__ means,
                                                   double* __restrict__ bmin,
                                                   double* __restrict__ bmax) {
    const int tid = threadIdx.x;
    const int c = blockIdx.x * 256 + tid;
    double s = 0.0;
#pragma unroll 8
    for (int k = 0; k < RCHUNKS; ++k) s += partials[(size_t)k * FEATS + c];
    const double m = s * (1.0 / (double)BATCH);  // /8192 exact pow2 scale
    means[c] = m;
    __shared__ double smin[256], smax[256];
    smin[tid] = m; smax[tid] = m; __syncthreads();
    for (int s2 = 128; s2 > 0; s2 >>= 1) {
        if (tid < s2) {
            smin[tid] = fmin(smin[tid], smin[tid + s2]);
            smax[tid] = fmax(smax[tid], smax[tid + s2]);
        }
        __syncthreads();
    }
    if (tid == 0) { bmin[blockIdx.x] = smin[0]; bmax[blockIdx.x] = smax[0]; }
}

__global__ __launch_bounds__(1024) void config_kernel(const double* __restrict__ means,
                                                      const double* __restrict__ bmin,
                                                      const double* __restrict__ bmax,
                                                      const float* __restrict__ noise,
                                                      float* __restrict__ scale) {
    __shared__ unsigned s_hist[FEATS + 1];
    __shared__ double s_sig[FEATS + 1];
    const int tid = threadIdx.x;

    double xmin = bmin[0], xmax = bmax[0];
#pragma unroll
    for (int i = 1; i < FEATS / 256; ++i) {  // 16 block partials, broadcast reads
        xmin = fmin(xmin, bmin[i]);
        xmax = fmax(xmax, bmax[i]);
    }
    for (int i = tid; i < FEATS + 1; i += 1024) s_hist[i] = 0;
    __syncthreads();

    int binr[4];
    double nz[4];
    const double denom = xmax - xmin;
#pragma unroll
    for (int k = 0; k < 4; ++k) {
        int c = tid + k * 1024;
        // match numpy op order: F*(x - xmin) then divide, truncate toward zero
        double b = ((double)FEATS * (means[c] - xmin)) / denom;
        int bi = (int)b;
        binr[k] = bi;
        nz[k] = (double)noise[c];
        atomicAdd(&s_hist[bi], 1u);
    }
    __syncthreads();

    const double K = -2.302585092994045684017991454684364208;  // ln(0.1)
    for (int i = tid; i < FEATS + 1; i += 1024) {
        unsigned cnt = s_hist[i];
        if (cnt) {
            double dr = (cnt == 1u) ? 0.1 : exp(K / (0.6 * (double)cnt));
            s_sig[i] = sqrt(dr / (1.0 - dr));
        }
    }
    __syncthreads();

#pragma unroll
    for (int k = 0; k < 4; ++k) {
        int c = tid + k * 1024;
        scale[c] = (float)(1.0 + s_sig[binr[k]] * nz[k]);
    }
}

__global__ __launch_bounds__(256) void scale_kernel(const v4f* __restrict__ in,
                                                    const v4f* __restrict__ scalev,
                                                    v4f* __restrict__ out) {
    const int base = blockIdx.x * 1024 + threadIdx.x;
#pragma unroll
    for (int k = 0; k < 4; ++k) {
        const int i = base + k * 256;
        v4f v = in[i];
        v4f s = scalev[i & (FEATS / 4 - 1)];
        v *= s;
        __builtin_nontemporal_store(v, &out[i]);  // out is write-once: don't evict L3-resident `in`
    }
}

extern "C" void kernel_launch(void* const* d_in, const int* in_sizes, int n_in,
                              void* d_out, int out_size, void* d_ws, size_t ws_size,
                              hipStream_t stream) {
    const float* in = (const float*)d_in[0];
    const float* noise = (const float*)d_in[1];
    float* out = (float*)d_out;
    double* partials = (double*)d_ws;
    double* means = partials + (size_t)RCHUNKS * FEATS;
    double* bmin = means + FEATS;
    double* bmax = bmin + 16;
    float* scale = (float*)(bmax + 16);

    dim3 g1(4, RCHUNKS);
    colsum_part<<<g1, 256, 0, stream>>>(in, partials);
    reduce_mean<<<FEATS / 256, 256, 0, stream>>>(partials, means, bmin, bmax);
    config_kernel<<<1, 1024, 0, stream>>>(means, bmin, bmax, noise, scale);
    scale_kernel<<<BATCH * FEATS / 4 / 1024, 256, 0, stream>>>(
        (const v4f*)in, (const v4f*)scale, (v4f*)out);
}